// Round 7
// baseline (375.898 us; speedup 1.0000x reference)
//
#include <hip/hip_runtime.h>
#include <hip/hip_bf16.h>
#include <math.h>

typedef unsigned short u16;
typedef unsigned int u32;
typedef __attribute__((ext_vector_type(8))) short bf8v;   // 8 bf16 in 4 VGPRs
typedef __attribute__((ext_vector_type(4))) float f32x4;

#define BR   16      // batch rows per block
#define LR   32      // logical rows (2 branches merged: same layer weights)
#define NLAY 4

// ws layout (u16 indices). Floats [0..1152) hold folded input proj (fp32).
#define U_IPH 4096                      // ipwT hi [4][256][64]
#define U_IPL (U_IPH + 65536)           // ipwT lo
#define U_XPH (U_IPL + 65536)           // xpwT hi [4][48][128] (cols>=36 zero)
#define U_XPL (U_XPH + 24576)
#define U_OPH (U_XPL + 24576)           // opwT hi [4][64][128]
#define U_OPL (U_OPH + 32768)           // end = 249856 u16 = 499712 B

__device__ __forceinline__ float b2f(u16 u) {
  u32 x = ((u32)u) << 16; return __uint_as_float(x);
}
__device__ __forceinline__ u16 f2b(float f) {   // RNE via HW cvt
  __hip_bfloat16 b = __float2bfloat16(f);
  return __builtin_bit_cast(u16, b);
}
__device__ __forceinline__ void splitbf(float v, u16& h, u16& l) {
  h = f2b(v);
  l = f2b(v - b2f(h));
}
__device__ __forceinline__ float siluf(float v) { return v / (1.f + __expf(-v)); }
__device__ __forceinline__ float softplusf(float v) {
  return v > 20.f ? v : log1pf(__expf(v));
}
// XOR-swizzled LDS indices (u16 units; 16B chunk = 8 elems) — conflict-free b128
__device__ __forceinline__ int sxIdx(int r, int c) {   // residual [32][64]
  return r * 64 + ((((c >> 3) ^ r) & 7) << 3) + (c & 7);
}
__device__ __forceinline__ int szIdx(int r, int c) {   // xc/y [32][128]
  int ch = c >> 3;
  int chs = (ch & 8) | ((ch ^ r) & 7);
  return r * 128 + chs * 8 + (c & 7);
}

#define MFMA16(A, B, C) __builtin_amdgcn_mfma_f32_16x16x32_bf16(A, B, C, 0, 0, 0)

// ---------------------------------------------------------------------------
// Prologue (single kernel): blocks 0..63 = NC-fold; blocks 64..543 = weight
// transpose + bf16 hi/lo split with coalesced reads.
// ---------------------------------------------------------------------------
extern "C" __global__ __launch_bounds__(256)
void prep_all_kernel(const float* __restrict__ w_nr, const float* __restrict__ b_nr,
                     const float* __restrict__ w_r,  const float* __restrict__ b_r,
                     const float* __restrict__ win_nr, const float* __restrict__ bin_nr,
                     const float* __restrict__ win_r,  const float* __restrict__ bin_r,
                     const float* __restrict__ ipw, const float* __restrict__ xpw,
                     const float* __restrict__ opw,
                     float* __restrict__ wsf, u16* __restrict__ wsu) {
  __shared__ float snr[1000];
  __shared__ float sr_[1000];
  const int bid = blockIdx.x, tid = threadIdx.x;
  if (bid < 64) {
    const int j = bid;           // output column 0..63
    for (int k = tid; k < 1000; k += 256) {
      snr[k] = win_nr[(size_t)k * 64 + j];
      sr_[k] = win_r [(size_t)k * 64 + j];
    }
    __syncthreads();
    const int grp = tid >> 4;
    const int ks  = tid & 15;
    const int k0 = ks * 63, k1 = (k0 + 63 < 1000) ? k0 + 63 : 1000;
    for (int o = grp; o < 18; o += 16) {
      float acc = 0.f;
      if (o < 12) {
        const float* s = w_nr + (size_t)o * 1000;
        for (int k = k0; k < k1; ++k) acc = fmaf(s[k], snr[k], acc);
      } else if (o == 12) {
        for (int k = k0; k < k1; ++k) acc = fmaf(b_nr[k], snr[k], acc);
      } else if (o < 17) {
        const float* s = w_r + (size_t)(o - 13) * 1000;
        for (int k = k0; k < k1; ++k) acc = fmaf(s[k], sr_[k], acc);
      } else {
        for (int k = k0; k < k1; ++k) acc = fmaf(b_r[k], sr_[k], acc);
      }
      for (int off = 1; off < 16; off <<= 1) acc += __shfl_xor(acc, off, 64);
      if (ks == 0) {
        if (o < 12)       wsf[o * 64 + j] = acc;
        else if (o == 12) wsf[768 + j]  = acc + bin_nr[j];
        else if (o < 17)  wsf[832 + (o - 13) * 64 + j] = acc;
        else              wsf[1088 + j] = acc + bin_r[j];
      }
    }
    return;
  }
  // ---- transform part: coalesced reads (dst-minor index fastest)
  int gid = (bid - 64) * 256 + tid;         // 0 .. 122879
  float v; int dh, dl;
  if (gid < 65536) {                        // ipw [64k][256n] -> [256n][64k]
    int l = gid >> 14, rem = gid & 16383;
    int n = rem & 255, k = rem >> 8;
    v = ipw[(size_t)l * 16384 + k * 256 + n];
    int o = l * 16384 + n * 64 + k;
    dh = U_IPH + o; dl = U_IPL + o;
  } else if (gid < 65536 + 18432) {         // xpw [128k][36n] -> [48n][128k]
    int e = gid - 65536;
    int l = e / 4608, r2 = e - l * 4608;
    int k = r2 / 36, n = r2 - k * 36;
    v = xpw[(size_t)l * 4608 + k * 36 + n];
    int o = l * 6144 + n * 128 + k;
    dh = U_XPH + o; dl = U_XPL + o;
  } else if (gid < 65536 + 18432 + 6144) {  // xpw pad cols 36..47 = 0
    int e = gid - 83968;
    int l = e / 1536, r3 = e - l * 1536;
    int n = 36 + (r3 >> 7), k = r3 & 127;
    v = 0.f;
    int o = l * 6144 + n * 128 + k;
    dh = U_XPH + o; dl = U_XPL + o;
  } else {                                  // opw [128k][64n] -> [64n][128k]
    int e = gid - 90112;
    int l = e >> 13, rem = e & 8191;
    int n = rem & 63, k = rem >> 6;
    v = opw[(size_t)l * 8192 + k * 64 + n];
    int o = l * 8192 + n * 128 + k;
    dh = U_OPH + o; dl = U_OPL + o;
  }
  u16 h, lo; splitbf(v, h, lo);
  wsu[dh] = h; wsu[dl] = lo;
}

// ---------------------------------------------------------------------------
// Main: 1024 blocks x 512 threads, 16 batch rows x 2 branches = 32 logical
// rows. GEMMs = bf16x3 MFMA (Ah*Bh + Al*Bh + Ah*Bl, fp32 accum, ~2^-17 rel).
// TLP design: VGPR <= 64 (8 waves/SIMD boundary, m69) + LDS ~41.7KB
// (3 blocks/CU). z lives in a wave-private flat f32 LDS buffer (same lane
// writes & reads -> no swizzle, no conflicts). proj+bc computed by 2 waves
// in-register; only 4 dt-cols + bc touch LDS.
// ---------------------------------------------------------------------------
extern "C" __global__ __launch_bounds__(512, 8)
void mamba_main_kernel(const float* __restrict__ xin, const float* __restrict__ wsf,
                       const u16* __restrict__ wsu,
                       const float* __restrict__ cw, const float* __restrict__ cbi,
                       const float* __restrict__ dtw, const float* __restrict__ dtb,
                       const float* __restrict__ dskip,
                       const float* __restrict__ lng, const float* __restrict__ lnb,
                       const float* __restrict__ hw1, const float* __restrict__ hb1,
                       const float* __restrict__ hw2, const float* __restrict__ hb2,
                       float* __restrict__ outp)
{
  __shared__ __align__(16) u16 sxh[LR * 64], sxl[LR * 64];     // residual hi/lo
  __shared__ __align__(16) u16 szh[LR * 128], szl[LR * 128];   // xc -> y (hi/lo)
  __shared__ __align__(16) float szz[8 * 512];   // z (f32, wave-private flat); head h1
  __shared__ __align__(16) float sdt[LR * 4];    // proj cols 0..3
  __shared__ float spart[4][LR][2];
  __shared__ float sbc[LR];

  const int tid = threadIdx.x;
  const int wv = tid >> 6, lane = tid & 63;
  const int col16 = lane & 15, g = lane >> 4;
  const int rt = wv & 1, cp = wv >> 1;       // row-half, col-pair
  const int rowA = rt * 16 + col16;
  const int r0 = blockIdx.x * BR;

  // ---- Phase 0: x0 = feat @ Wf + bf (folded through NC)
  for (int idx = tid; idx < LR * 64; idx += 512) {
    int r = idx >> 6, c = idx & 63;
    const float* xr = xin + (size_t)(r0 + (r & 15)) * 16;
    float acc;
    if (r < 16) {
      acc = wsf[768 + c];
      #pragma unroll
      for (int i = 0; i < 12; ++i) acc = fmaf(xr[i], wsf[i * 64 + c], acc);
    } else {
      acc = wsf[1088 + c];
      #pragma unroll
      for (int i = 0; i < 4; ++i) acc = fmaf(xr[12 + i], wsf[832 + i * 64 + c], acc);
    }
    u16 h, lo; splitbf(acc, h, lo);
    int di = sxIdx(r, c); sxh[di] = h; sxl[di] = lo;
  }

  for (int l = 0; l < NLAY; ++l) {
    __syncthreads();
    const u16* iph = wsu + U_IPH + l * 16384;
    const u16* ipl_ = wsu + U_IPL + l * 16384;

    // ---- Phase 1: xz = x @ ipwT (K=64). Wave owns xc tiles {2cp,2cp+1} and
    //      z tiles {8+2cp,9+2cp}. xc -> szh/szl; z -> szz (f32, flat, private).
    {
      f32x4 Cf[4] = {{0,0,0,0},{0,0,0,0},{0,0,0,0},{0,0,0,0}};
      #pragma unroll
      for (int ks = 0; ks < 2; ++ks) {
        int ch = ks * 4 + g;
        int ai = rowA * 64 + (((ch ^ rowA) & 7) << 3);
        bf8v Ah = *(const bf8v*)&sxh[ai];
        bf8v Al = *(const bf8v*)&sxl[ai];
        #pragma unroll
        for (int t = 0; t < 4; ++t) {
          int nt = (t < 2) ? (cp * 2 + t) : (8 + cp * 2 + (t - 2));
          int n = nt * 16 + col16;
          bf8v Wh = *(const bf8v*)&iph[n * 64 + ks * 32 + g * 8];
          bf8v Wl = *(const bf8v*)&ipl_[n * 64 + ks * 32 + g * 8];
          Cf[t] = MFMA16(Ah, Wh, Cf[t]);
          Cf[t] = MFMA16(Al, Wh, Cf[t]);
          Cf[t] = MFMA16(Ah, Wl, Cf[t]);
        }
      }
      #pragma unroll
      for (int t = 0; t < 2; ++t) {          // xc: conv tap3 + silu -> LDS
        int col = cp * 32 + t * 16 + col16;
        float c3 = cw[(size_t)l * 512 + col * 4 + 3];
        float cc = cbi[(size_t)l * 128 + col];
        #pragma unroll
        for (int j = 0; j < 4; ++j) {
          float v = siluf(fmaf(Cf[t][j], c3, cc));
          u16 h, lo; splitbf(v, h, lo);
          int di = szIdx(rt * 16 + g * 4 + j, col);
          szh[di] = h; szl[di] = lo;
        }
      }
      #pragma unroll
      for (int t = 0; t < 2; ++t)            // z: silu -> flat f32 LDS
        #pragma unroll
        for (int j = 0; j < 4; ++j)
          szz[wv * 512 + (t * 4 + j) * 64 + lane] = siluf(Cf[t + 2][j]);
    }
    __syncthreads();
    // ---- Phase 2+3: waves 0-1 compute proj (16 rows x 48 cols each, in-reg),
    //      then bc = Bm.Cm in-lane (cols c and c+16 live in the same lane) and
    //      dt-cols 0..3 -> sdt. Scan collapses (h = dBx at L=1).
    if (wv < 2) {
      const u16* xph = wsu + U_XPH + l * 6144;
      const u16* xpl = wsu + U_XPL + l * 6144;
      f32x4 P[3] = {{0,0,0,0},{0,0,0,0},{0,0,0,0}};
      #pragma unroll
      for (int ks = 0; ks < 4; ++ks) {
        int ch = ks * 4 + g;
        int ai = rowA * 128 + (((ch & 8) | ((ch ^ rowA) & 7)) << 3);
        bf8v Ah = *(const bf8v*)&szh[ai];
        bf8v Al = *(const bf8v*)&szl[ai];
        #pragma unroll
        for (int t = 0; t < 3; ++t) {
          int n = t * 16 + col16;
          bf8v Wh = *(const bf8v*)&xph[n * 128 + ks * 32 + g * 8];
          bf8v Wl = *(const bf8v*)&xpl[n * 128 + ks * 32 + g * 8];
          P[t] = MFMA16(Ah, Wh, P[t]);
          P[t] = MFMA16(Al, Wh, P[t]);
          P[t] = MFMA16(Ah, Wl, P[t]);
        }
      }
      if (col16 < 4) {                       // dt inputs (proj cols 0..3)
        #pragma unroll
        for (int j = 0; j < 4; ++j)
          sdt[(rt * 16 + g * 4 + j) * 4 + col16] = P[0][j];
      }
      f32x4 prod;                            // bc pairing: col c * col c+16
      #pragma unroll
      for (int j = 0; j < 4; ++j)
        prod[j] = (col16 >= 4) ? P[0][j] * P[1][j] : P[1][j] * P[2][j];
      #pragma unroll
      for (int m = 1; m < 16; m <<= 1)
        #pragma unroll
        for (int j = 0; j < 4; ++j) prod[j] += __shfl_xor(prod[j], m);
      if (col16 == 0) {
        #pragma unroll
        for (int j = 0; j < 4; ++j) sbc[rt * 16 + g * 4 + j] = prod[j];
      }
    }
    __syncthreads();
    // ---- Phase 4: dt = softplus(proj[:,:4]@dtw+dtb); y = xc*(dt*bc+ds)*silu(z)
    //      xc from szh/szl; z from szz (same lane that wrote it).
    {
      #pragma unroll
      for (int t = 0; t < 2; ++t) {
        int col = cp * 32 + t * 16 + col16;
        float w0 = dtw[(size_t)l * 512 + col];
        float w1 = dtw[(size_t)l * 512 + 128 + col];
        float w2 = dtw[(size_t)l * 512 + 256 + col];
        float w3 = dtw[(size_t)l * 512 + 384 + col];
        float bb = dtb[(size_t)l * 128 + col];
        float ds = dskip[(size_t)l * 128 + col];
        #pragma unroll
        for (int j = 0; j < 4; ++j) {
          int r = rt * 16 + g * 4 + j;
          float4 pj = *(const float4*)&sdt[r * 4];
          float dtv = softplusf(fmaf(pj.w, w3, fmaf(pj.z, w2, fmaf(pj.y, w1, fmaf(pj.x, w0, bb)))));
          int di = szIdx(r, col);
          float xc = b2f(szh[di]) + b2f(szl[di]);
          float zv = szz[wv * 512 + (t * 4 + j) * 64 + lane];
          float y = xc * fmaf(dtv, sbc[r], ds) * zv;
          u16 h, lo; splitbf(y, h, lo);
          szh[di] = h; szl[di] = lo;
        }
      }
    }
    __syncthreads();
    // ---- Phase 5: o = y @ opwT (32x64, K=128); 1 tile/wave; LN partials
    f32x4 O = {0, 0, 0, 0};
    {
      const u16* oph = wsu + U_OPH + l * 8192;
      const u16* opl = wsu + U_OPL + l * 8192;
      #pragma unroll
      for (int ks = 0; ks < 4; ++ks) {
        int ch = ks * 4 + g;
        int ai = rowA * 128 + (((ch & 8) | ((ch ^ rowA) & 7)) << 3);
        bf8v Ah = *(const bf8v*)&szh[ai];
        bf8v Al = *(const bf8v*)&szl[ai];
        int n = cp * 16 + col16;
        bf8v Wh = *(const bf8v*)&oph[n * 128 + ks * 32 + g * 8];
        bf8v Wl = *(const bf8v*)&opl[n * 128 + ks * 32 + g * 8];
        O = MFMA16(Ah, Wh, O);
        O = MFMA16(Al, Wh, O);
        O = MFMA16(Ah, Wl, O);
      }
      #pragma unroll
      for (int j = 0; j < 4; ++j) {
        float s1 = O[j], s2 = O[j] * O[j];
        s1 += __shfl_xor(s1, 1); s2 += __shfl_xor(s2, 1);
        s1 += __shfl_xor(s1, 2); s2 += __shfl_xor(s2, 2);
        s1 += __shfl_xor(s1, 4); s2 += __shfl_xor(s2, 4);
        s1 += __shfl_xor(s1, 8); s2 += __shfl_xor(s2, 8);
        if (col16 == 0) {
          int row = rt * 16 + g * 4 + j;
          spart[cp][row][0] = s1; spart[cp][row][1] = s2;
        }
      }
    }
    __syncthreads();
    // ---- Phase 6: per-lane LN stats + x += LN(o)*g + b (O still in regs)
    {
      int col = cp * 16 + col16;
      float gv = lng[(size_t)l * 64 + col], bv = lnb[(size_t)l * 64 + col];
      #pragma unroll
      for (int j = 0; j < 4; ++j) {
        int row = rt * 16 + g * 4 + j;
        float s1 = spart[0][row][0] + spart[1][row][0] + spart[2][row][0] + spart[3][row][0];
        float s2 = spart[0][row][1] + spart[1][row][1] + spart[2][row][1] + spart[3][row][1];
        float m = s1 * (1.f / 64);
        float var = s2 * (1.f / 64) - m * m;
        float rstd = rsqrtf(var + 1e-5f);
        float v = fmaf((O[j] - m) * rstd, gv, bv);
        int di = sxIdx(row, col);
        float nv = b2f(sxh[di]) + b2f(sxl[di]) + v;
        u16 h, lo; splitbf(nv, h, lo);
        sxh[di] = h; sxl[di] = lo;
      }
    }
  }
  __syncthreads();
  // ---- Head stage A: transpose hw1 [128][32] -> szh/szl (bf16 hi/lo, swizzled)
  {
    int k = tid >> 2, n0 = (tid & 3) * 8;
    const float* src = hw1 + (size_t)k * 32 + n0;
    #pragma unroll
    for (int i = 0; i < 8; ++i) {
      u16 h, lo; splitbf(src[i], h, lo);
      int di = szIdx(n0 + i, k);
      szh[di] = h; szl[di] = lo;
    }
  }
  __syncthreads();
  // ---- Head stage B: h1 = relu([x_nr|x_r] @ hw1 + hb1) via MFMA (waves 0-1)
  if (wv < 2) {
    f32x4 H = {0, 0, 0, 0};
    const int m = col16;                 // batch row
    #pragma unroll
    for (int ks = 0; ks < 4; ++ks) {
      int kg = ks * 32 + g * 8;          // concat-k
      int ai = sxIdx(m + ((kg >> 6) << 4), kg & 63);
      bf8v Ah = *(const bf8v*)&sxh[ai];
      bf8v Al = *(const bf8v*)&sxl[ai];
      int ch = ks * 4 + g;
      int n = wv * 16 + col16;
      int bi = n * 128 + (((ch & 8) | ((ch ^ n) & 7)) << 3);
      bf8v Bh = *(const bf8v*)&szh[bi];
      bf8v Bl = *(const bf8v*)&szl[bi];
      H = MFMA16(Ah, Bh, H);
      H = MFMA16(Al, Bh, H);
      H = MFMA16(Ah, Bl, H);
    }
    float bias = hb1[wv * 16 + col16];
    #pragma unroll
    for (int j = 0; j < 4; ++j) {
      int row = g * 4 + j;
      szz[row * 32 + wv * 16 + col16] = fmaxf(H[j] + bias, 0.f);
    }
  }
  __syncthreads();
  // ---- Head stage C: out = h1 @ hw2 + hb2
  if (tid < 256) {
    int r = tid >> 4, s = tid & 15;
    float acc = szz[r * 32 + s] * hw2[s] + szz[r * 32 + 16 + s] * hw2[16 + s];
    acc += __shfl_xor(acc, 1); acc += __shfl_xor(acc, 2);
    acc += __shfl_xor(acc, 4); acc += __shfl_xor(acc, 8);
    if (s == 0) outp[r0 + r] = acc + hb2[0];
  }
}

extern "C" void kernel_launch(void* const* d_in, const int* in_sizes, int n_in,
                              void* d_out, int out_size, void* d_ws, size_t ws_size,
                              hipStream_t stream) {
  const float* x      = (const float*)d_in[0];
  const float* w_nr   = (const float*)d_in[1];
  const float* b_nr   = (const float*)d_in[2];
  const float* w_r    = (const float*)d_in[3];
  const float* b_r    = (const float*)d_in[4];
  const float* win_nr = (const float*)d_in[5];
  const float* bin_nr = (const float*)d_in[6];
  const float* win_r  = (const float*)d_in[7];
  const float* bin_r  = (const float*)d_in[8];
  const float* ipw    = (const float*)d_in[9];
  const float* cw     = (const float*)d_in[10];
  const float* cb     = (const float*)d_in[11];
  const float* xpw    = (const float*)d_in[12];
  const float* dtw    = (const float*)d_in[13];
  const float* dtb    = (const float*)d_in[14];
  // d_in[15] = alog: dead at L=1 (scan from h=0 uses only dBx)
  const float* dskip  = (const float*)d_in[16];
  const float* opw    = (const float*)d_in[17];
  const float* lng    = (const float*)d_in[18];
  const float* lnb    = (const float*)d_in[19];
  const float* hw1    = (const float*)d_in[20];
  const float* hb1    = (const float*)d_in[21];
  const float* hw2    = (const float*)d_in[22];
  const float* hb2    = (const float*)d_in[23];
  float* wsf = (float*)d_ws;
  u16*   wsu = (u16*)d_ws;
  float* out = (float*)d_out;

  prep_all_kernel<<<544, 256, 0, stream>>>(w_nr, b_nr, w_r, b_r,
                                           win_nr, bin_nr, win_r, bin_r,
                                           ipw, xpw, opw, wsf, wsu);
  mamba_main_kernel<<<16384 / BR, 512, 0, stream>>>(x, wsf, wsu, cw, cb,
                                                    dtw, dtb, dskip, lng, lnb,
                                                    hw1, hb1, hw2, hb2, out);
}

// Round 8
// 362.094 us; speedup vs baseline: 1.0381x; 1.0381x over previous
//
#include <hip/hip_runtime.h>
#include <hip/hip_bf16.h>
#include <math.h>

typedef unsigned short u16;
typedef unsigned int u32;
typedef __attribute__((ext_vector_type(8))) short bf8v;   // 8 bf16 in 4 VGPRs
typedef __attribute__((ext_vector_type(4))) float f32x4;

#define BR   32      // batch rows per block
#define LR   64      // logical rows (2 branches merged: same layer weights)
#define NLAY 4

// ws layout (u16 indices). Floats [0..1152) hold folded input proj (fp32).
#define U_IPH 4096                      // ipwT hi [4][256][64]
#define U_IPL (U_IPH + 65536)           // ipwT lo
#define U_XPH (U_IPL + 65536)           // xpwT hi [4][48][128] (cols>=36 zero)
#define U_XPL (U_XPH + 24576)
#define U_OPH (U_XPL + 24576)           // opwT hi [4][64][128]
#define U_OPL (U_OPH + 32768)           // end = 249856 u16 = 499712 B

__device__ __forceinline__ float b2f(u16 u) {
  u32 x = ((u32)u) << 16; return __uint_as_float(x);
}
__device__ __forceinline__ u16 f2b(float f) {   // RNE via HW cvt
  __hip_bfloat16 b = __float2bfloat16(f);
  return __builtin_bit_cast(u16, b);
}
__device__ __forceinline__ void splitbf(float v, u16& h, u16& l) {
  h = f2b(v);
  l = f2b(v - b2f(h));
}
__device__ __forceinline__ float siluf(float v) { return v / (1.f + __expf(-v)); }
__device__ __forceinline__ float softplusf(float v) {
  // branch-free: max(v,0) + log(1+exp(-|v|)); exact for large |v|, ~7 VALU
  return fmaxf(v, 0.f) + __logf(1.f + __expf(-fabsf(v)));
}
// XOR-swizzled LDS indices (u16 units; 16B chunk = 8 elems) — conflict-free b128
__device__ __forceinline__ int sxIdx(int r, int c) {   // residual [64][64]
  return r * 64 + ((((c >> 3) ^ r) & 7) << 3) + (c & 7);
}
__device__ __forceinline__ int szIdx(int r, int c) {   // xc/y/z [64][128]
  int ch = c >> 3;
  int chs = (ch & 8) | ((ch ^ r) & 7);
  return r * 128 + chs * 8 + (c & 7);
}

#define MFMA16(A, B, C) __builtin_amdgcn_mfma_f32_16x16x32_bf16(A, B, C, 0, 0, 0)

// ---------------------------------------------------------------------------
// Prologue (single kernel): blocks 0..63 = NC-fold; blocks 64..543 = weight
// transpose + bf16 hi/lo split with coalesced reads.
// ---------------------------------------------------------------------------
extern "C" __global__ __launch_bounds__(256)
void prep_all_kernel(const float* __restrict__ w_nr, const float* __restrict__ b_nr,
                     const float* __restrict__ w_r,  const float* __restrict__ b_r,
                     const float* __restrict__ win_nr, const float* __restrict__ bin_nr,
                     const float* __restrict__ win_r,  const float* __restrict__ bin_r,
                     const float* __restrict__ ipw, const float* __restrict__ xpw,
                     const float* __restrict__ opw,
                     float* __restrict__ wsf, u16* __restrict__ wsu) {
  __shared__ float snr[1000];
  __shared__ float sr_[1000];
  const int bid = blockIdx.x, tid = threadIdx.x;
  if (bid < 64) {
    const int j = bid;           // output column 0..63
    for (int k = tid; k < 1000; k += 256) {
      snr[k] = win_nr[(size_t)k * 64 + j];
      sr_[k] = win_r [(size_t)k * 64 + j];
    }
    __syncthreads();
    const int grp = tid >> 4;
    const int ks  = tid & 15;
    const int k0 = ks * 63, k1 = (k0 + 63 < 1000) ? k0 + 63 : 1000;
    for (int o = grp; o < 18; o += 16) {
      float acc = 0.f;
      if (o < 12) {
        const float* s = w_nr + (size_t)o * 1000;
        for (int k = k0; k < k1; ++k) acc = fmaf(s[k], snr[k], acc);
      } else if (o == 12) {
        for (int k = k0; k < k1; ++k) acc = fmaf(b_nr[k], snr[k], acc);
      } else if (o < 17) {
        const float* s = w_r + (size_t)(o - 13) * 1000;
        for (int k = k0; k < k1; ++k) acc = fmaf(s[k], sr_[k], acc);
      } else {
        for (int k = k0; k < k1; ++k) acc = fmaf(b_r[k], sr_[k], acc);
      }
      for (int off = 1; off < 16; off <<= 1) acc += __shfl_xor(acc, off, 64);
      if (ks == 0) {
        if (o < 12)       wsf[o * 64 + j] = acc;
        else if (o == 12) wsf[768 + j]  = acc + bin_nr[j];
        else if (o < 17)  wsf[832 + (o - 13) * 64 + j] = acc;
        else              wsf[1088 + j] = acc + bin_r[j];
      }
    }
    return;
  }
  // ---- transform part: coalesced reads (dst-minor index fastest)
  int gid = (bid - 64) * 256 + tid;         // 0 .. 122879
  float v; int dh, dl;
  if (gid < 65536) {                        // ipw [64k][256n] -> [256n][64k]
    int l = gid >> 14, rem = gid & 16383;
    int n = rem & 255, k = rem >> 8;
    v = ipw[(size_t)l * 16384 + k * 256 + n];
    int o = l * 16384 + n * 64 + k;
    dh = U_IPH + o; dl = U_IPL + o;
  } else if (gid < 65536 + 18432) {         // xpw [128k][36n] -> [48n][128k]
    int e = gid - 65536;
    int l = e / 4608, r2 = e - l * 4608;
    int k = r2 / 36, n = r2 - k * 36;
    v = xpw[(size_t)l * 4608 + k * 36 + n];
    int o = l * 6144 + n * 128 + k;
    dh = U_XPH + o; dl = U_XPL + o;
  } else if (gid < 65536 + 18432 + 6144) {  // xpw pad cols 36..47 = 0
    int e = gid - 83968;
    int l = e / 1536, r3 = e - l * 1536;
    int n = 36 + (r3 >> 7), k = r3 & 127;
    v = 0.f;
    int o = l * 6144 + n * 128 + k;
    dh = U_XPH + o; dl = U_XPL + o;
  } else {                                  // opw [128k][64n] -> [64n][128k]
    int e = gid - 90112;
    int l = e >> 13, rem = e & 8191;
    int n = rem & 63, k = rem >> 6;
    v = opw[(size_t)l * 8192 + k * 64 + n];
    int o = l * 8192 + n * 128 + k;
    dh = U_OPH + o; dl = U_OPL + o;
  }
  u16 h, lo; splitbf(v, h, lo);
  wsu[dh] = h; wsu[dl] = lo;
}

// ---------------------------------------------------------------------------
// Main: 512 blocks x 512 threads (exactly 2 blocks/CU, one round).
// Block = 32 batch rows x 2 branches = 64 logical rows (shared weights).
// GEMMs = bf16x3 MFMA. Ph1 is weight-stationary (W-frags held over 4 row
// tiles -> 4x less ip-weight L2 traffic). All 8 waves active every phase.
// z stored as single-bf16 plane (szb). LDS = 80.1 KB -> 2 blocks/CU.
// ---------------------------------------------------------------------------
extern "C" __global__ __launch_bounds__(512, 4)
void mamba_main_kernel(const float* __restrict__ xin, const float* __restrict__ wsf,
                       const u16* __restrict__ wsu,
                       const float* __restrict__ cw, const float* __restrict__ cbi,
                       const float* __restrict__ dtw, const float* __restrict__ dtb,
                       const float* __restrict__ dskip,
                       const float* __restrict__ lng, const float* __restrict__ lnb,
                       const float* __restrict__ hw1, const float* __restrict__ hb1,
                       const float* __restrict__ hw2, const float* __restrict__ hb2,
                       float* __restrict__ outp)
{
  __shared__ __align__(16) u16 sxh[LR * 64], sxl[LR * 64];     // residual hi/lo
  __shared__ __align__(16) u16 szh[LR * 128], szl[LR * 128];   // xc -> y hi/lo
  __shared__ __align__(16) u16 szb[LR * 128];                  // z (bf16 single)
  __shared__ __align__(16) float sproj[LR * 48];               // proj; later h1
  __shared__ float spart[4][LR][2];
  __shared__ float sbc[LR];

  const int tid = threadIdx.x;
  const int wv = tid >> 6, lane = tid & 63;
  const int col16 = lane & 15, g = lane >> 4;
  const int r0 = blockIdx.x * BR;

  // ---- Phase 0: x0 = feat @ Wf + bf (folded through NC). rows 0-31 nr, 32-63 r
  for (int idx = tid; idx < LR * 64; idx += 512) {
    int r = idx >> 6, c = idx & 63;
    const float* xr = xin + (size_t)(r0 + (r & 31)) * 16;
    float acc;
    if (r < 32) {
      acc = wsf[768 + c];
      #pragma unroll
      for (int i = 0; i < 12; ++i) acc = fmaf(xr[i], wsf[i * 64 + c], acc);
    } else {
      acc = wsf[1088 + c];
      #pragma unroll
      for (int i = 0; i < 4; ++i) acc = fmaf(xr[12 + i], wsf[832 + i * 64 + c], acc);
    }
    u16 h, lo; splitbf(acc, h, lo);
    int di = sxIdx(r, c); sxh[di] = h; sxl[di] = lo;
  }

  for (int l = 0; l < NLAY; ++l) {
    __syncthreads();
    // ---- Phase 1: xz = x @ ipwT (M=64,K=64,N=256), weight-stationary.
    //      Wave owns n-tiles {2wv, 2wv+1}: wv<4 -> xc (cols 0-127),
    //      wv>=4 -> z (cols 0-127 of z half). 48 MFMA/wave.
    {
      const u16* iph = wsu + U_IPH + l * 16384;
      const u16* ipl_ = wsu + U_IPL + l * 16384;
      const bool isZ = (wv >= 4);
      #pragma unroll
      for (int tt = 0; tt < 2; ++tt) {
        const int tile = 2 * wv + tt;          // 0..15
        const int n = tile * 16 + col16;
        // W frags for both k-halves, held across all 4 row-tiles
        bf8v Wh0 = *(const bf8v*)&iph[n * 64 + g * 8];
        bf8v Wl0 = *(const bf8v*)&ipl_[n * 64 + g * 8];
        bf8v Wh1 = *(const bf8v*)&iph[n * 64 + 32 + g * 8];
        bf8v Wl1 = *(const bf8v*)&ipl_[n * 64 + 32 + g * 8];
        float c3 = 0.f, cc = 0.f;
        int colx = (tile & 7) * 16 + col16;    // output col within its half
        if (!isZ) {
          c3 = cw[(size_t)l * 512 + colx * 4 + 3];
          cc = cbi[(size_t)l * 128 + colx];
        }
        for (int rt = 0; rt < 4; ++rt) {
          const int rowA = rt * 16 + col16;
          bf8v Ah0 = *(const bf8v*)&sxh[rowA * 64 + (((g ^ rowA) & 7) << 3)];
          bf8v Al0 = *(const bf8v*)&sxl[rowA * 64 + (((g ^ rowA) & 7) << 3)];
          bf8v Ah1 = *(const bf8v*)&sxh[rowA * 64 + ((((4 + g) ^ rowA) & 7) << 3)];
          bf8v Al1 = *(const bf8v*)&sxl[rowA * 64 + ((((4 + g) ^ rowA) & 7) << 3)];
          f32x4 acc = {0, 0, 0, 0};
          acc = MFMA16(Ah0, Wh0, acc);
          acc = MFMA16(Al0, Wh0, acc);
          acc = MFMA16(Ah0, Wl0, acc);
          acc = MFMA16(Ah1, Wh1, acc);
          acc = MFMA16(Al1, Wh1, acc);
          acc = MFMA16(Ah1, Wl1, acc);
          #pragma unroll
          for (int j = 0; j < 4; ++j) {
            int row = rt * 16 + g * 4 + j;
            if (!isZ) {                        // xc: conv tap3 + silu -> hi/lo
              float v = siluf(fmaf(acc[j], c3, cc));
              u16 h, lo; splitbf(v, h, lo);
              int di = szIdx(row, colx);
              szh[di] = h; szl[di] = lo;
            } else {                           // z: silu -> single bf16
              szb[szIdx(row, colx)] = f2b(siluf(acc[j]));
            }
          }
        }
      }
    }
    __syncthreads();
    // ---- Phase 2: proj = xc @ xpwT (M=64,K=128,N=48). 12 tasks over 8 waves:
    //      wv<4: (rt=wv, nt=0,1); wv>=4: (rt=wv-4, nt=2).
    {
      const u16* xph = wsu + U_XPH + l * 6144;
      const u16* xpl = wsu + U_XPL + l * 6144;
      const int rt = wv & 3;
      const int rowA = rt * 16 + col16;
      const int ntasks = (wv < 4) ? 2 : 1;
      for (int q = 0; q < ntasks; ++q) {
        const int nt = (wv < 4) ? q : 2;
        const int n2 = nt * 16 + col16;
        f32x4 C = {0, 0, 0, 0};
        #pragma unroll
        for (int ks = 0; ks < 4; ++ks) {
          int ch = ks * 4 + g;
          int ai = rowA * 128 + (((ch & 8) | ((ch ^ rowA) & 7)) << 3);
          bf8v Ah = *(const bf8v*)&szh[ai];
          bf8v Al = *(const bf8v*)&szl[ai];
          bf8v Wh = *(const bf8v*)&xph[n2 * 128 + ks * 32 + g * 8];
          bf8v Wl = *(const bf8v*)&xpl[n2 * 128 + ks * 32 + g * 8];
          C = MFMA16(Ah, Wh, C);
          C = MFMA16(Al, Wh, C);
          C = MFMA16(Ah, Wl, C);
        }
        #pragma unroll
        for (int j = 0; j < 4; ++j)
          sproj[(rt * 16 + g * 4 + j) * 48 + nt * 16 + col16] = C[j];
      }
    }
    __syncthreads();
    // ---- Phase 3: bc[r] = Bm . Cm  (scan collapses: h = dBx at L=1)
    {
      int r = tid >> 3, s = tid & 7;
      float v = sproj[r * 48 + 4 + s] * sproj[r * 48 + 20 + s]
              + sproj[r * 48 + 12 + s] * sproj[r * 48 + 28 + s];
      v += __shfl_xor(v, 1); v += __shfl_xor(v, 2); v += __shfl_xor(v, 4);
      if (s == 0) sbc[r] = v;
    }
    __syncthreads();
    // ---- Phase 4: dt = softplus(proj[:,:4]@dtw+dtb); y = xc*(dt*bc+ds)*z
    //      Wave w: rows rt=w&3, cols [(w>>2)*64, +64). All from LDS.
    {
      const int rt = wv & 3;
      const int ctb = (wv >> 2) * 4;
      #pragma unroll
      for (int t = 0; t < 4; ++t) {
        int col = (ctb + t) * 16 + col16;
        float w0 = dtw[(size_t)l * 512 + col];
        float w1 = dtw[(size_t)l * 512 + 128 + col];
        float w2 = dtw[(size_t)l * 512 + 256 + col];
        float w3 = dtw[(size_t)l * 512 + 384 + col];
        float bb = dtb[(size_t)l * 128 + col];
        float ds = dskip[(size_t)l * 128 + col];
        #pragma unroll
        for (int j = 0; j < 4; ++j) {
          int r = rt * 16 + g * 4 + j;
          float4 pj = *(const float4*)&sproj[r * 48];
          float dtv = softplusf(fmaf(pj.w, w3, fmaf(pj.z, w2, fmaf(pj.y, w1, fmaf(pj.x, w0, bb)))));
          int di = szIdx(r, col);
          float xc = b2f(szh[di]) + b2f(szl[di]);
          float zv = b2f(szb[di]);
          float y = xc * fmaf(dtv, sbc[r], ds) * zv;
          u16 h, lo; splitbf(y, h, lo);
          szh[di] = h; szl[di] = lo;
        }
      }
    }
    __syncthreads();
    // ---- Phase 5: o = y @ opwT (M=64,K=128,N=64). 16 tasks / 8 waves:
    //      wave w: nt = w&3, row-pair rtp = w>>2 -> rts {2rtp, 2rtp+1}.
    f32x4 O0 = {0,0,0,0}, O1 = {0,0,0,0};
    {
      const u16* oph = wsu + U_OPH + l * 8192;
      const u16* opl = wsu + U_OPL + l * 8192;
      const int nt = wv & 3, rtp = wv >> 2;
      const int n = nt * 16 + col16;
      #pragma unroll
      for (int ks = 0; ks < 4; ++ks) {
        bf8v Wh = *(const bf8v*)&oph[n * 128 + ks * 32 + g * 8];
        bf8v Wl = *(const bf8v*)&opl[n * 128 + ks * 32 + g * 8];
        int ch = ks * 4 + g;
        #pragma unroll
        for (int rr = 0; rr < 2; ++rr) {
          int rowA = (2 * rtp + rr) * 16 + col16;
          int ai = rowA * 128 + (((ch & 8) | ((ch ^ rowA) & 7)) << 3);
          bf8v Ah = *(const bf8v*)&szh[ai];
          bf8v Al = *(const bf8v*)&szl[ai];
          if (rr == 0) {
            O0 = MFMA16(Ah, Wh, O0); O0 = MFMA16(Al, Wh, O0); O0 = MFMA16(Ah, Wl, O0);
          } else {
            O1 = MFMA16(Ah, Wh, O1); O1 = MFMA16(Al, Wh, O1); O1 = MFMA16(Ah, Wl, O1);
          }
        }
      }
      #pragma unroll
      for (int rr = 0; rr < 2; ++rr) {
        #pragma unroll
        for (int j = 0; j < 4; ++j) {
          float o = (rr == 0) ? O0[j] : O1[j];
          float s1 = o, s2 = o * o;
          s1 += __shfl_xor(s1, 1); s2 += __shfl_xor(s2, 1);
          s1 += __shfl_xor(s1, 2); s2 += __shfl_xor(s2, 2);
          s1 += __shfl_xor(s1, 4); s2 += __shfl_xor(s2, 4);
          s1 += __shfl_xor(s1, 8); s2 += __shfl_xor(s2, 8);
          if (col16 == 0) {
            int row = (2 * rtp + rr) * 16 + g * 4 + j;
            spart[nt][row][0] = s1; spart[nt][row][1] = s2;
          }
        }
      }
    }
    __syncthreads();
    // ---- Phase 6: LN stats per lane + x += LN(o)*g + b (O0/O1 still live)
    {
      const int nt = wv & 3, rtp = wv >> 2;
      int col = nt * 16 + col16;
      float gv = lng[(size_t)l * 64 + col], bv = lnb[(size_t)l * 64 + col];
      #pragma unroll
      for (int rr = 0; rr < 2; ++rr) {
        #pragma unroll
        for (int j = 0; j < 4; ++j) {
          int row = (2 * rtp + rr) * 16 + g * 4 + j;
          float s1 = spart[0][row][0] + spart[1][row][0] + spart[2][row][0] + spart[3][row][0];
          float s2 = spart[0][row][1] + spart[1][row][1] + spart[2][row][1] + spart[3][row][1];
          float m = s1 * (1.f / 64);
          float var = s2 * (1.f / 64) - m * m;
          float rstd = rsqrtf(var + 1e-5f);
          float o = (rr == 0) ? O0[j] : O1[j];
          float v = fmaf((o - m) * rstd, gv, bv);
          int di = sxIdx(row, col);
          float nv = b2f(sxh[di]) + b2f(sxl[di]) + v;
          u16 h, lo; splitbf(nv, h, lo);
          sxh[di] = h; sxl[di] = lo;
        }
      }
    }
  }
  __syncthreads();
  // ---- Head stage A: transpose hw1 [128][32] -> szh/szl rows 0-31 (swizzled)
  {
    int k = tid >> 2, n0 = (tid & 3) * 8;
    const float* src = hw1 + (size_t)k * 32 + n0;
    #pragma unroll
    for (int i = 0; i < 8; ++i) {
      u16 h, lo; splitbf(src[i], h, lo);
      int di = szIdx(n0 + i, k);
      szh[di] = h; szl[di] = lo;
    }
  }
  __syncthreads();
  // ---- Head stage B: h1 = relu([x_nr|x_r] @ hw1 + hb1), waves 0-3:
  //      (mt = w&1, nt = w>>1). A rows: logical row = m + (k>=64 ? 32 : 0).
  if (wv < 4) {
    const int mt = wv & 1, nt = wv >> 1;
    const int m16 = mt * 16 + col16;
    const int nB = nt * 16 + col16;
    f32x4 H = {0, 0, 0, 0};
    #pragma unroll
    for (int ks = 0; ks < 4; ++ks) {
      int kg = ks * 32 + g * 8;
      int arow = m16 + ((kg >> 6) << 5);     // +32 for rain half
      int ai = sxIdx(arow, kg & 63);
      bf8v Ah = *(const bf8v*)&sxh[ai];
      bf8v Al = *(const bf8v*)&sxl[ai];
      int bi = szIdx(nB, kg);
      bf8v Bh = *(const bf8v*)&szh[bi];
      bf8v Bl = *(const bf8v*)&szl[bi];
      H = MFMA16(Ah, Bh, H);
      H = MFMA16(Al, Bh, H);
      H = MFMA16(Ah, Bl, H);
    }
    float bias = hb1[nB];
    #pragma unroll
    for (int j = 0; j < 4; ++j) {
      int m = mt * 16 + g * 4 + j;
      sproj[m * 48 + nB] = fmaxf(H[j] + bias, 0.f);
    }
  }
  __syncthreads();
  // ---- Head stage C: out = h1 @ hw2 + hb2
  if (tid < 256) {
    int m = tid >> 3, s = tid & 7;
    float acc = sproj[m * 48 + s] * hw2[s]
              + sproj[m * 48 + 8 + s] * hw2[8 + s]
              + sproj[m * 48 + 16 + s] * hw2[16 + s]
              + sproj[m * 48 + 24 + s] * hw2[24 + s];
    acc += __shfl_xor(acc, 1); acc += __shfl_xor(acc, 2); acc += __shfl_xor(acc, 4);
    if (s == 0) outp[r0 + m] = acc + hb2[0];
  }
}

extern "C" void kernel_launch(void* const* d_in, const int* in_sizes, int n_in,
                              void* d_out, int out_size, void* d_ws, size_t ws_size,
                              hipStream_t stream) {
  const float* x      = (const float*)d_in[0];
  const float* w_nr   = (const float*)d_in[1];
  const float* b_nr   = (const float*)d_in[2];
  const float* w_r    = (const float*)d_in[3];
  const float* b_r    = (const float*)d_in[4];
  const float* win_nr = (const float*)d_in[5];
  const float* bin_nr = (const float*)d_in[6];
  const float* win_r  = (const float*)d_in[7];
  const float* bin_r  = (const float*)d_in[8];
  const float* ipw    = (const float*)d_in[9];
  const float* cw     = (const float*)d_in[10];
  const float* cb     = (const float*)d_in[11];
  const float* xpw    = (const float*)d_in[12];
  const float* dtw    = (const float*)d_in[13];
  const float* dtb    = (const float*)d_in[14];
  // d_in[15] = alog: dead at L=1 (scan from h=0 uses only dBx)
  const float* dskip  = (const float*)d_in[16];
  const float* opw    = (const float*)d_in[17];
  const float* lng    = (const float*)d_in[18];
  const float* lnb    = (const float*)d_in[19];
  const float* hw1    = (const float*)d_in[20];
  const float* hb1    = (const float*)d_in[21];
  const float* hw2    = (const float*)d_in[22];
  const float* hb2    = (const float*)d_in[23];
  float* wsf = (float*)d_ws;
  u16*   wsu = (u16*)d_ws;
  float* out = (float*)d_out;

  prep_all_kernel<<<544, 256, 0, stream>>>(w_nr, b_nr, w_r, b_r,
                                           win_nr, bin_nr, win_r, bin_r,
                                           ipw, xpw, opw, wsf, wsu);
  mamba_main_kernel<<<16384 / BR, 512, 0, stream>>>(x, wsf, wsu, cw, cb,
                                                    dtw, dtb, dskip, lng, lnb,
                                                    hw1, hb1, hw2, hb2, out);
}

// Round 9
// 225.213 us; speedup vs baseline: 1.6691x; 1.6078x over previous
//
#include <hip/hip_runtime.h>
#include <hip/hip_bf16.h>
#include <math.h>

typedef unsigned short u16;
typedef unsigned int u32;
typedef __attribute__((ext_vector_type(8))) short bf8v;   // 8 bf16 in 4 VGPRs
typedef __attribute__((ext_vector_type(4))) float f32x4;

#define BR   32      // batch rows per block
#define LR   64      // logical rows (2 branches merged: same layer weights)
#define NLAY 4

// ws layout (u16 indices). Floats [0..1152) hold folded input proj (fp32).
#define U_IPH 4096                      // ipwT hi [4][256][64]
#define U_IPL (U_IPH + 65536)           // ipwT lo
#define U_XPH (U_IPL + 65536)           // xpwT hi [4][48][128] (cols>=36 zero)
#define U_XPL (U_XPH + 24576)
#define U_OPH (U_XPL + 24576)           // opwT hi [4][64][128]
#define U_OPL (U_OPH + 32768)           // end = 249856 u16 = 499712 B

__device__ __forceinline__ float b2f(u16 u) {
  u32 x = ((u32)u) << 16; return __uint_as_float(x);
}
__device__ __forceinline__ u16 f2b(float f) {   // RNE via HW cvt
  __hip_bfloat16 b = __float2bfloat16(f);
  return __builtin_bit_cast(u16, b);
}
__device__ __forceinline__ void splitbf(float v, u16& h, u16& l) {
  h = f2b(v);
  l = f2b(v - b2f(h));
}
__device__ __forceinline__ float siluf(float v) { return v / (1.f + __expf(-v)); }
__device__ __forceinline__ float softplusf(float v) {
  // branch-free: max(v,0) + log(1+exp(-|v|)); exact for large |v|, ~7 VALU
  return fmaxf(v, 0.f) + __logf(1.f + __expf(-fabsf(v)));
}
// XOR-swizzled LDS indices (u16 units; 16B chunk = 8 elems) — conflict-free b128
__device__ __forceinline__ int sxIdx(int r, int c) {   // residual [64][64]
  return r * 64 + ((((c >> 3) ^ r) & 7) << 3) + (c & 7);
}
__device__ __forceinline__ int szIdx(int r, int c) {   // xc/y/z [64][128]
  int ch = c >> 3;
  int chs = (ch & 8) | ((ch ^ r) & 7);
  return r * 128 + chs * 8 + (c & 7);
}

#define MFMA16(A, B, C) __builtin_amdgcn_mfma_f32_16x16x32_bf16(A, B, C, 0, 0, 0)

// ---------------------------------------------------------------------------
// Prologue (single kernel): blocks 0..63 = NC-fold; blocks 64..543 = weight
// transpose + bf16 hi/lo split with coalesced reads.
// ---------------------------------------------------------------------------
extern "C" __global__ __launch_bounds__(256)
void prep_all_kernel(const float* __restrict__ w_nr, const float* __restrict__ b_nr,
                     const float* __restrict__ w_r,  const float* __restrict__ b_r,
                     const float* __restrict__ win_nr, const float* __restrict__ bin_nr,
                     const float* __restrict__ win_r,  const float* __restrict__ bin_r,
                     const float* __restrict__ ipw, const float* __restrict__ xpw,
                     const float* __restrict__ opw,
                     float* __restrict__ wsf, u16* __restrict__ wsu) {
  __shared__ float snr[1000];
  __shared__ float sr_[1000];
  const int bid = blockIdx.x, tid = threadIdx.x;
  if (bid < 64) {
    const int j = bid;           // output column 0..63
    for (int k = tid; k < 1000; k += 256) {
      snr[k] = win_nr[(size_t)k * 64 + j];
      sr_[k] = win_r [(size_t)k * 64 + j];
    }
    __syncthreads();
    const int grp = tid >> 4;
    const int ks  = tid & 15;
    const int k0 = ks * 63, k1 = (k0 + 63 < 1000) ? k0 + 63 : 1000;
    for (int o = grp; o < 18; o += 16) {
      float acc = 0.f;
      if (o < 12) {
        const float* s = w_nr + (size_t)o * 1000;
        for (int k = k0; k < k1; ++k) acc = fmaf(s[k], snr[k], acc);
      } else if (o == 12) {
        for (int k = k0; k < k1; ++k) acc = fmaf(b_nr[k], snr[k], acc);
      } else if (o < 17) {
        const float* s = w_r + (size_t)(o - 13) * 1000;
        for (int k = k0; k < k1; ++k) acc = fmaf(s[k], sr_[k], acc);
      } else {
        for (int k = k0; k < k1; ++k) acc = fmaf(b_r[k], sr_[k], acc);
      }
      for (int off = 1; off < 16; off <<= 1) acc += __shfl_xor(acc, off, 64);
      if (ks == 0) {
        if (o < 12)       wsf[o * 64 + j] = acc;
        else if (o == 12) wsf[768 + j]  = acc + bin_nr[j];
        else if (o < 17)  wsf[832 + (o - 13) * 64 + j] = acc;
        else              wsf[1088 + j] = acc + bin_r[j];
      }
    }
    return;
  }
  // ---- transform part: coalesced reads (dst-minor index fastest)
  int gid = (bid - 64) * 256 + tid;         // 0 .. 122879
  float v; int dh, dl;
  if (gid < 65536) {                        // ipw [64k][256n] -> [256n][64k]
    int l = gid >> 14, rem = gid & 16383;
    int n = rem & 255, k = rem >> 8;
    v = ipw[(size_t)l * 16384 + k * 256 + n];
    int o = l * 16384 + n * 64 + k;
    dh = U_IPH + o; dl = U_IPL + o;
  } else if (gid < 65536 + 18432) {         // xpw [128k][36n] -> [48n][128k]
    int e = gid - 65536;
    int l = e / 4608, r2 = e - l * 4608;
    int k = r2 / 36, n = r2 - k * 36;
    v = xpw[(size_t)l * 4608 + k * 36 + n];
    int o = l * 6144 + n * 128 + k;
    dh = U_XPH + o; dl = U_XPL + o;
  } else if (gid < 65536 + 18432 + 6144) {  // xpw pad cols 36..47 = 0
    int e = gid - 83968;
    int l = e / 1536, r3 = e - l * 1536;
    int n = 36 + (r3 >> 7), k = r3 & 127;
    v = 0.f;
    int o = l * 6144 + n * 128 + k;
    dh = U_XPH + o; dl = U_XPL + o;
  } else {                                  // opw [128k][64n] -> [64n][128k]
    int e = gid - 90112;
    int l = e >> 13, rem = e & 8191;
    int n = rem & 63, k = rem >> 6;
    v = opw[(size_t)l * 8192 + k * 64 + n];
    int o = l * 8192 + n * 128 + k;
    dh = U_OPH + o; dl = U_OPL + o;
  }
  u16 h, lo; splitbf(v, h, lo);
  wsu[dh] = h; wsu[dl] = lo;
}

// ---------------------------------------------------------------------------
// Main: 512 blocks x 512 threads (2 blocks/CU, one round). Block = 32 batch
// rows x 2 branches = 64 logical rows. GEMMs = bf16x3 MFMA. Ph1 is
// weight-stationary but SERIALIZED (#pragma unroll 1) so only one tile's
// W-frags (16 VGPR) + one row-tile's A-frags (16 VGPR) are live at once —
// r8's (512,4) build allocated 64 VGPR and spilled 194MB/launch to scratch.
// launch_bounds(512,3): empirically spill-free (r6: 76 VGPR, 64KB writes).
// ---------------------------------------------------------------------------
extern "C" __global__ __launch_bounds__(512, 3)
void mamba_main_kernel(const float* __restrict__ xin, const float* __restrict__ wsf,
                       const u16* __restrict__ wsu,
                       const float* __restrict__ cw, const float* __restrict__ cbi,
                       const float* __restrict__ dtw, const float* __restrict__ dtb,
                       const float* __restrict__ dskip,
                       const float* __restrict__ lng, const float* __restrict__ lnb,
                       const float* __restrict__ hw1, const float* __restrict__ hb1,
                       const float* __restrict__ hw2, const float* __restrict__ hb2,
                       float* __restrict__ outp)
{
  __shared__ __align__(16) u16 sxh[LR * 64], sxl[LR * 64];     // residual hi/lo
  __shared__ __align__(16) u16 szh[LR * 128], szl[LR * 128];   // xc -> y hi/lo
  __shared__ __align__(16) u16 szb[LR * 128];                  // z (bf16 single)
  __shared__ __align__(16) float sproj[LR * 48];               // proj; later h1
  __shared__ float spart[4][LR][2];
  __shared__ float sbc[LR];

  const int tid = threadIdx.x;
  const int wv = tid >> 6, lane = tid & 63;
  const int col16 = lane & 15, g = lane >> 4;
  const int r0 = blockIdx.x * BR;

  // ---- Phase 0: x0 = feat @ Wf + bf (folded through NC). rows 0-31 nr, 32-63 r
  for (int idx = tid; idx < LR * 64; idx += 512) {
    int r = idx >> 6, c = idx & 63;
    const float* xr = xin + (size_t)(r0 + (r & 31)) * 16;
    float acc;
    if (r < 32) {
      acc = wsf[768 + c];
      #pragma unroll
      for (int i = 0; i < 12; ++i) acc = fmaf(xr[i], wsf[i * 64 + c], acc);
    } else {
      acc = wsf[1088 + c];
      #pragma unroll
      for (int i = 0; i < 4; ++i) acc = fmaf(xr[12 + i], wsf[832 + i * 64 + c], acc);
    }
    u16 h, lo; splitbf(acc, h, lo);
    int di = sxIdx(r, c); sxh[di] = h; sxl[di] = lo;
  }

  for (int l = 0; l < NLAY; ++l) {
    __syncthreads();
    // ---- Phase 1: xz = x @ ipwT (M=64,K=64,N=256), weight-stationary,
    //      serialized tiles. Wave owns n-tiles {2wv, 2wv+1}: wv<4 -> xc,
    //      wv>=4 -> z. 48 MFMA/wave, W-frags held across the 4 row tiles.
    {
      const u16* iph = wsu + U_IPH + l * 16384;
      const u16* ipl_ = wsu + U_IPL + l * 16384;
      const bool isZ = (wv >= 4);
      #pragma unroll 1
      for (int tt = 0; tt < 2; ++tt) {
        const int tile = 2 * wv + tt;          // 0..15
        const int n = tile * 16 + col16;
        // W frags for both k-halves, held across all 4 row-tiles
        bf8v Wh0 = *(const bf8v*)&iph[n * 64 + g * 8];
        bf8v Wl0 = *(const bf8v*)&ipl_[n * 64 + g * 8];
        bf8v Wh1 = *(const bf8v*)&iph[n * 64 + 32 + g * 8];
        bf8v Wl1 = *(const bf8v*)&ipl_[n * 64 + 32 + g * 8];
        float c3 = 0.f, cc = 0.f;
        int colx = (tile & 7) * 16 + col16;    // output col within its half
        if (!isZ) {
          c3 = cw[(size_t)l * 512 + colx * 4 + 3];
          cc = cbi[(size_t)l * 128 + colx];
        }
        #pragma unroll 1
        for (int rt = 0; rt < 4; ++rt) {
          const int rowA = rt * 16 + col16;
          bf8v Ah0 = *(const bf8v*)&sxh[rowA * 64 + (((g ^ rowA) & 7) << 3)];
          bf8v Al0 = *(const bf8v*)&sxl[rowA * 64 + (((g ^ rowA) & 7) << 3)];
          bf8v Ah1 = *(const bf8v*)&sxh[rowA * 64 + ((((4 + g) ^ rowA) & 7) << 3)];
          bf8v Al1 = *(const bf8v*)&sxl[rowA * 64 + ((((4 + g) ^ rowA) & 7) << 3)];
          f32x4 acc = {0, 0, 0, 0};
          acc = MFMA16(Ah0, Wh0, acc);
          acc = MFMA16(Al0, Wh0, acc);
          acc = MFMA16(Ah0, Wl0, acc);
          acc = MFMA16(Ah1, Wh1, acc);
          acc = MFMA16(Al1, Wh1, acc);
          acc = MFMA16(Ah1, Wl1, acc);
          #pragma unroll
          for (int j = 0; j < 4; ++j) {
            int row = rt * 16 + g * 4 + j;
            if (!isZ) {                        // xc: conv tap3 + silu -> hi/lo
              float v = siluf(fmaf(acc[j], c3, cc));
              u16 h, lo; splitbf(v, h, lo);
              int di = szIdx(row, colx);
              szh[di] = h; szl[di] = lo;
            } else {                           // z: silu -> single bf16
              szb[szIdx(row, colx)] = f2b(siluf(acc[j]));
            }
          }
        }
      }
    }
    __syncthreads();
    // ---- Phase 2: proj = xc @ xpwT (M=64,K=128,N=48). 12 tasks over 8 waves:
    //      wv<4: (rt=wv, nt=0,1); wv>=4: (rt=wv-4, nt=2).
    {
      const u16* xph = wsu + U_XPH + l * 6144;
      const u16* xpl = wsu + U_XPL + l * 6144;
      const int rt = wv & 3;
      const int rowA = rt * 16 + col16;
      const int ntasks = (wv < 4) ? 2 : 1;
      #pragma unroll 1
      for (int q = 0; q < ntasks; ++q) {
        const int nt = (wv < 4) ? q : 2;
        const int n2 = nt * 16 + col16;
        f32x4 C = {0, 0, 0, 0};
        #pragma unroll
        for (int ks = 0; ks < 4; ++ks) {
          int ch = ks * 4 + g;
          int ai = rowA * 128 + (((ch & 8) | ((ch ^ rowA) & 7)) << 3);
          bf8v Ah = *(const bf8v*)&szh[ai];
          bf8v Al = *(const bf8v*)&szl[ai];
          bf8v Wh = *(const bf8v*)&xph[n2 * 128 + ks * 32 + g * 8];
          bf8v Wl = *(const bf8v*)&xpl[n2 * 128 + ks * 32 + g * 8];
          C = MFMA16(Ah, Wh, C);
          C = MFMA16(Al, Wh, C);
          C = MFMA16(Ah, Wl, C);
        }
        #pragma unroll
        for (int j = 0; j < 4; ++j)
          sproj[(rt * 16 + g * 4 + j) * 48 + nt * 16 + col16] = C[j];
      }
    }
    __syncthreads();
    // ---- Phase 3: bc[r] = Bm . Cm  (scan collapses: h = dBx at L=1)
    {
      int r = tid >> 3, s = tid & 7;
      float v = sproj[r * 48 + 4 + s] * sproj[r * 48 + 20 + s]
              + sproj[r * 48 + 12 + s] * sproj[r * 48 + 28 + s];
      v += __shfl_xor(v, 1); v += __shfl_xor(v, 2); v += __shfl_xor(v, 4);
      if (s == 0) sbc[r] = v;
    }
    __syncthreads();
    // ---- Phase 4: dt = softplus(proj[:,:4]@dtw+dtb); y = xc*(dt*bc+ds)*z
    //      Wave w: rows rt=w&3, cols [(w>>2)*64, +64). All from LDS.
    {
      const int rt = wv & 3;
      const int ctb = (wv >> 2) * 4;
      #pragma unroll 1
      for (int t = 0; t < 4; ++t) {
        int col = (ctb + t) * 16 + col16;
        float w0 = dtw[(size_t)l * 512 + col];
        float w1 = dtw[(size_t)l * 512 + 128 + col];
        float w2 = dtw[(size_t)l * 512 + 256 + col];
        float w3 = dtw[(size_t)l * 512 + 384 + col];
        float bb = dtb[(size_t)l * 128 + col];
        float ds = dskip[(size_t)l * 128 + col];
        #pragma unroll
        for (int j = 0; j < 4; ++j) {
          int r = rt * 16 + g * 4 + j;
          float4 pj = *(const float4*)&sproj[r * 48];
          float dtv = softplusf(fmaf(pj.w, w3, fmaf(pj.z, w2, fmaf(pj.y, w1, fmaf(pj.x, w0, bb)))));
          int di = szIdx(r, col);
          float xc = b2f(szh[di]) + b2f(szl[di]);
          float zv = b2f(szb[di]);
          float y = xc * fmaf(dtv, sbc[r], ds) * zv;
          u16 h, lo; splitbf(y, h, lo);
          szh[di] = h; szl[di] = lo;
        }
      }
    }
    __syncthreads();
    // ---- Phase 5: o = y @ opwT (M=64,K=128,N=64). 16 tasks / 8 waves:
    //      wave w: nt = w&3, row-pair rtp = w>>2 -> rts {2rtp, 2rtp+1}.
    f32x4 O0 = {0,0,0,0}, O1 = {0,0,0,0};
    {
      const u16* oph = wsu + U_OPH + l * 8192;
      const u16* opl = wsu + U_OPL + l * 8192;
      const int nt = wv & 3, rtp = wv >> 2;
      const int n = nt * 16 + col16;
      #pragma unroll
      for (int ks = 0; ks < 4; ++ks) {
        bf8v Wh = *(const bf8v*)&oph[n * 128 + ks * 32 + g * 8];
        bf8v Wl = *(const bf8v*)&opl[n * 128 + ks * 32 + g * 8];
        int ch = ks * 4 + g;
        #pragma unroll
        for (int rr = 0; rr < 2; ++rr) {
          int rowA = (2 * rtp + rr) * 16 + col16;
          int ai = rowA * 128 + (((ch & 8) | ((ch ^ rowA) & 7)) << 3);
          bf8v Ah = *(const bf8v*)&szh[ai];
          bf8v Al = *(const bf8v*)&szl[ai];
          if (rr == 0) {
            O0 = MFMA16(Ah, Wh, O0); O0 = MFMA16(Al, Wh, O0); O0 = MFMA16(Ah, Wl, O0);
          } else {
            O1 = MFMA16(Ah, Wh, O1); O1 = MFMA16(Al, Wh, O1); O1 = MFMA16(Ah, Wl, O1);
          }
        }
      }
      #pragma unroll
      for (int rr = 0; rr < 2; ++rr) {
        #pragma unroll
        for (int j = 0; j < 4; ++j) {
          float o = (rr == 0) ? O0[j] : O1[j];
          float s1 = o, s2 = o * o;
          s1 += __shfl_xor(s1, 1); s2 += __shfl_xor(s2, 1);
          s1 += __shfl_xor(s1, 2); s2 += __shfl_xor(s2, 2);
          s1 += __shfl_xor(s1, 4); s2 += __shfl_xor(s2, 4);
          s1 += __shfl_xor(s1, 8); s2 += __shfl_xor(s2, 8);
          if (col16 == 0) {
            int row = (2 * rtp + rr) * 16 + g * 4 + j;
            spart[nt][row][0] = s1; spart[nt][row][1] = s2;
          }
        }
      }
    }
    __syncthreads();
    // ---- Phase 6: LN stats per lane + x += LN(o)*g + b (O0/O1 still live)
    {
      const int nt = wv & 3, rtp = wv >> 2;
      int col = nt * 16 + col16;
      float gv = lng[(size_t)l * 64 + col], bv = lnb[(size_t)l * 64 + col];
      #pragma unroll
      for (int rr = 0; rr < 2; ++rr) {
        #pragma unroll
        for (int j = 0; j < 4; ++j) {
          int row = (2 * rtp + rr) * 16 + g * 4 + j;
          float s1 = spart[0][row][0] + spart[1][row][0] + spart[2][row][0] + spart[3][row][0];
          float s2 = spart[0][row][1] + spart[1][row][1] + spart[2][row][1] + spart[3][row][1];
          float m = s1 * (1.f / 64);
          float var = s2 * (1.f / 64) - m * m;
          float rstd = rsqrtf(var + 1e-5f);
          float o = (rr == 0) ? O0[j] : O1[j];
          float v = fmaf((o - m) * rstd, gv, bv);
          int di = sxIdx(row, col);
          float nv = b2f(sxh[di]) + b2f(sxl[di]) + v;
          u16 h, lo; splitbf(nv, h, lo);
          sxh[di] = h; sxl[di] = lo;
        }
      }
    }
  }
  __syncthreads();
  // ---- Head stage A: transpose hw1 [128][32] -> szh/szl rows 0-31 (swizzled)
  {
    int k = tid >> 2, n0 = (tid & 3) * 8;
    const float* src = hw1 + (size_t)k * 32 + n0;
    #pragma unroll
    for (int i = 0; i < 8; ++i) {
      u16 h, lo; splitbf(src[i], h, lo);
      int di = szIdx(n0 + i, k);
      szh[di] = h; szl[di] = lo;
    }
  }
  __syncthreads();
  // ---- Head stage B: h1 = relu([x_nr|x_r] @ hw1 + hb1), waves 0-3:
  //      (mt = w&1, nt = w>>1). A rows: logical row = m + (k>=64 ? 32 : 0).
  if (wv < 4) {
    const int mt = wv & 1, nt = wv >> 1;
    const int m16 = mt * 16 + col16;
    const int nB = nt * 16 + col16;
    f32x4 H = {0, 0, 0, 0};
    #pragma unroll
    for (int ks = 0; ks < 4; ++ks) {
      int kg = ks * 32 + g * 8;
      int arow = m16 + ((kg >> 6) << 5);     // +32 for rain half
      int ai = sxIdx(arow, kg & 63);
      bf8v Ah = *(const bf8v*)&sxh[ai];
      bf8v Al = *(const bf8v*)&sxl[ai];
      int bi = szIdx(nB, kg);
      bf8v Bh = *(const bf8v*)&szh[bi];
      bf8v Bl = *(const bf8v*)&szl[bi];
      H = MFMA16(Ah, Bh, H);
      H = MFMA16(Al, Bh, H);
      H = MFMA16(Ah, Bl, H);
    }
    float bias = hb1[nB];
    #pragma unroll
    for (int j = 0; j < 4; ++j) {
      int m = mt * 16 + g * 4 + j;
      sproj[m * 48 + nB] = fmaxf(H[j] + bias, 0.f);
    }
  }
  __syncthreads();
  // ---- Head stage C: out = h1 @ hw2 + hb2
  if (tid < 256) {
    int m = tid >> 3, s = tid & 7;
    float acc = sproj[m * 48 + s] * hw2[s]
              + sproj[m * 48 + 8 + s] * hw2[8 + s]
              + sproj[m * 48 + 16 + s] * hw2[16 + s]
              + sproj[m * 48 + 24 + s] * hw2[24 + s];
    acc += __shfl_xor(acc, 1); acc += __shfl_xor(acc, 2); acc += __shfl_xor(acc, 4);
    if (s == 0) outp[r0 + m] = acc + hb2[0];
  }
}

extern "C" void kernel_launch(void* const* d_in, const int* in_sizes, int n_in,
                              void* d_out, int out_size, void* d_ws, size_t ws_size,
                              hipStream_t stream) {
  const float* x      = (const float*)d_in[0];
  const float* w_nr   = (const float*)d_in[1];
  const float* b_nr   = (const float*)d_in[2];
  const float* w_r    = (const float*)d_in[3];
  const float* b_r    = (const float*)d_in[4];
  const float* win_nr = (const float*)d_in[5];
  const float* bin_nr = (const float*)d_in[6];
  const float* win_r  = (const float*)d_in[7];
  const float* bin_r  = (const float*)d_in[8];
  const float* ipw    = (const float*)d_in[9];
  const float* cw     = (const float*)d_in[10];
  const float* cb     = (const float*)d_in[11];
  const float* xpw    = (const float*)d_in[12];
  const float* dtw    = (const float*)d_in[13];
  const float* dtb    = (const float*)d_in[14];
  // d_in[15] = alog: dead at L=1 (scan from h=0 uses only dBx)
  const float* dskip  = (const float*)d_in[16];
  const float* opw    = (const float*)d_in[17];
  const float* lng    = (const float*)d_in[18];
  const float* lnb    = (const float*)d_in[19];
  const float* hw1    = (const float*)d_in[20];
  const float* hb1    = (const float*)d_in[21];
  const float* hw2    = (const float*)d_in[22];
  const float* hb2    = (const float*)d_in[23];
  float* wsf = (float*)d_ws;
  u16*   wsu = (u16*)d_ws;
  float* out = (float*)d_out;

  prep_all_kernel<<<544, 256, 0, stream>>>(w_nr, b_nr, w_r, b_r,
                                           win_nr, bin_nr, win_r, bin_r,
                                           ipw, xpw, opw, wsf, wsu);
  mamba_main_kernel<<<16384 / BR, 512, 0, stream>>>(x, wsf, wsu, cw, cb,
                                                    dtw, dtb, dskip, lng, lnb,
                                                    hw1, hb1, hw2, hb2, out);
}

// Round 10
// 206.791 us; speedup vs baseline: 1.8178x; 1.0891x over previous
//
#include <hip/hip_runtime.h>
#include <hip/hip_bf16.h>
#include <math.h>

typedef unsigned short u16;
typedef unsigned int u32;
typedef __attribute__((ext_vector_type(8))) short bf8v;   // 8 bf16 in 4 VGPRs
typedef __attribute__((ext_vector_type(4))) float f32x4;

#define BR   32      // batch rows per block
#define LR   64      // logical rows (2 branches merged: same layer weights)
#define NLAY 4

// ws layout (u16 indices). Floats [0..1152) hold folded input proj (fp32).
#define U_IPH 4096                      // ipwT hi [4][256][64]
#define U_IPL (U_IPH + 65536)           // ipwT lo
#define U_XPH (U_IPL + 65536)           // xpwT hi [4][48][128] (cols>=36 zero)
#define U_XPL (U_XPH + 24576)
#define U_OPH (U_XPL + 24576)           // opwT hi [4][64][128]
#define U_OPL (U_OPH + 32768)           // end = 249856 u16 = 499712 B

__device__ __forceinline__ float b2f(u16 u) {
  u32 x = ((u32)u) << 16; return __uint_as_float(x);
}
__device__ __forceinline__ u16 f2b(float f) {   // RNE via HW cvt
  __hip_bfloat16 b = __float2bfloat16(f);
  return __builtin_bit_cast(u16, b);
}
__device__ __forceinline__ void splitbf(float v, u16& h, u16& l) {
  h = f2b(v);
  l = f2b(v - b2f(h));
}
__device__ __forceinline__ float siluf(float v) { return v / (1.f + __expf(-v)); }
__device__ __forceinline__ float softplusf(float v) {
  // branch-free: max(v,0) + log(1+exp(-|v|)); exact for large |v|, ~7 VALU
  return fmaxf(v, 0.f) + __logf(1.f + __expf(-fabsf(v)));
}
// XOR-swizzled LDS indices (u16 units; 16B chunk = 8 elems) — conflict-free b128
__device__ __forceinline__ int sxIdx(int r, int c) {   // residual [64][64]
  return r * 64 + ((((c >> 3) ^ r) & 7) << 3) + (c & 7);
}
__device__ __forceinline__ int szIdx(int r, int c) {   // xc/y/z [64][128]
  int ch = c >> 3;
  int chs = (ch & 8) | ((ch ^ r) & 7);
  return r * 128 + chs * 8 + (c & 7);
}

#define MFMA16(A, B, C) __builtin_amdgcn_mfma_f32_16x16x32_bf16(A, B, C, 0, 0, 0)

// ---------------------------------------------------------------------------
// Prologue, 42 blocks x 256 threads, all accesses coalesced:
//   blocks 0..17  : NC-fold, one output row o per block; lane j = out column,
//                   win[k][j] reads are 256B contiguous, w[o][k] is scalar.
//   blocks 18..33 : ipw 64x64 LDS-tile transpose + bf16 hi/lo split.
//   blocks 34..37 : xpw (one per layer), 128x36(+pad 48) transpose.
//   blocks 38..41 : opw (one per layer), 128x64 transpose.
// ---------------------------------------------------------------------------
extern "C" __global__ __launch_bounds__(256)
void prep_all_kernel(const float* __restrict__ w_nr, const float* __restrict__ b_nr,
                     const float* __restrict__ w_r,  const float* __restrict__ b_r,
                     const float* __restrict__ win_nr, const float* __restrict__ bin_nr,
                     const float* __restrict__ win_r,  const float* __restrict__ bin_r,
                     const float* __restrict__ ipw, const float* __restrict__ xpw,
                     const float* __restrict__ opw,
                     float* __restrict__ wsf, u16* __restrict__ wsu) {
  __shared__ float tileF[128 * 65];     // max: opw 128x64 (+pad); fold uses 256
  const int bid = blockIdx.x, tid = threadIdx.x;
  const int lane = tid & 63, wv4 = tid >> 6;

  if (bid < 18) {
    // ---- NC-fold: out row o = bid. Wave s handles k-slice [250s, 250s+250).
    const int o = bid;
    const float* win = (o < 13) ? win_nr : win_r;
    const float* wr;
    if (o < 12)       wr = w_nr + (size_t)o * 1000;
    else if (o == 12) wr = b_nr;
    else if (o < 17)  wr = w_r + (size_t)(o - 13) * 1000;
    else              wr = b_r;
    float acc = 0.f;
    const int k0 = wv4 * 250, k1 = k0 + 250;
    for (int k = k0; k < k1; ++k)
      acc = fmaf(wr[k], win[(size_t)k * 64 + lane], acc);
    tileF[wv4 * 64 + lane] = acc;
    __syncthreads();
    if (tid < 64) {
      float v = tileF[tid] + tileF[64 + tid] + tileF[128 + tid] + tileF[192 + tid];
      if (o < 12)       wsf[o * 64 + tid] = v;
      else if (o == 12) wsf[768 + tid]  = v + bin_nr[tid];
      else if (o < 17)  wsf[832 + (o - 13) * 64 + tid] = v;
      else              wsf[1088 + tid] = v + bin_r[tid];
    }
    return;
  }

  if (bid < 34) {
    // ---- ipw [64k][256n] -> [256n][64k] hi/lo, 64x64 tile per block
    const int t = bid - 18;
    const int l = t >> 2, n0 = (t & 3) * 64;
    #pragma unroll
    for (int rr = 0; rr < 16; ++rr) {
      int k = rr * 4 + wv4;
      tileF[k * 65 + lane] = ipw[(size_t)l * 16384 + k * 256 + n0 + lane];
    }
    __syncthreads();
    const int n = tid >> 2, kc = tid & 3;        // 64 n x 4 k-chunks of 16
    size_t o = (size_t)l * 16384 + (n0 + n) * 64 + kc * 16;
    #pragma unroll
    for (int c = 0; c < 2; ++c) {
      bf8v hv, lv;
      #pragma unroll
      for (int i = 0; i < 8; ++i) {
        int k = kc * 16 + c * 8 + i;
        u16 h, lo; splitbf(tileF[k * 65 + n], h, lo);
        hv[i] = (short)h; lv[i] = (short)lo;
      }
      *(bf8v*)&wsu[U_IPH + o + c * 8] = hv;
      *(bf8v*)&wsu[U_IPL + o + c * 8] = lv;
    }
    return;
  }

  if (bid < 38) {
    // ---- xpw [128k][36n] -> [48n][128k] hi/lo (cols 36..47 zero), per layer
    const int l = bid - 34;
    for (int idx = tid; idx < 4608; idx += 256) {
      int k = idx / 36, n = idx - k * 36;
      tileF[k * 37 + n] = xpw[(size_t)l * 4608 + idx];
    }
    __syncthreads();
    if (tid < 192) {
      const int n = tid >> 2, kc = tid & 3;      // 48 n x 4 k-chunks of 32
      size_t o = (size_t)l * 6144 + n * 128 + kc * 32;
      #pragma unroll
      for (int c = 0; c < 4; ++c) {
        bf8v hv, lv;
        #pragma unroll
        for (int i = 0; i < 8; ++i) {
          int k = kc * 32 + c * 8 + i;
          float v = (n < 36) ? tileF[k * 37 + n] : 0.f;
          u16 h, lo; splitbf(v, h, lo);
          hv[i] = (short)h; lv[i] = (short)lo;
        }
        *(bf8v*)&wsu[U_XPH + o + c * 8] = hv;
        *(bf8v*)&wsu[U_XPL + o + c * 8] = lv;
      }
    }
    return;
  }

  {
    // ---- opw [128k][64n] -> [64n][128k] hi/lo, per layer
    const int l = bid - 38;
    #pragma unroll
    for (int rr = 0; rr < 32; ++rr) {
      int k = rr * 4 + wv4;
      tileF[k * 65 + lane] = opw[(size_t)l * 8192 + k * 64 + lane];
    }
    __syncthreads();
    const int n = tid >> 2, kc = tid & 3;        // 64 n x 4 k-chunks of 32
    size_t o = (size_t)l * 8192 + n * 128 + kc * 32;
    #pragma unroll
    for (int c = 0; c < 4; ++c) {
      bf8v hv, lv;
      #pragma unroll
      for (int i = 0; i < 8; ++i) {
        int k = kc * 32 + c * 8 + i;
        u16 h, lo; splitbf(tileF[k * 65 + n], h, lo);
        hv[i] = (short)h; lv[i] = (short)lo;
      }
      *(bf8v*)&wsu[U_OPH + o + c * 8] = hv;
      *(bf8v*)&wsu[U_OPL + o + c * 8] = lv;
    }
  }
}

// ---------------------------------------------------------------------------
// Main: 512 blocks x 512 threads (2 blocks/CU, one round). Block = 32 batch
// rows x 2 branches = 64 logical rows. GEMMs = bf16x3 MFMA. Ph1 is
// weight-stationary but SERIALIZED (#pragma unroll 1) so only one tile's
// W-frags (16 VGPR) + one row-tile's A-frags (16 VGPR) are live at once.
// launch_bounds(512,3): spill-free (r9: 64 VGPR, WRITE_SIZE 64KB).
// UNCHANGED from round 9 (107 us) — this round touches only the prologue.
// ---------------------------------------------------------------------------
extern "C" __global__ __launch_bounds__(512, 3)
void mamba_main_kernel(const float* __restrict__ xin, const float* __restrict__ wsf,
                       const u16* __restrict__ wsu,
                       const float* __restrict__ cw, const float* __restrict__ cbi,
                       const float* __restrict__ dtw, const float* __restrict__ dtb,
                       const float* __restrict__ dskip,
                       const float* __restrict__ lng, const float* __restrict__ lnb,
                       const float* __restrict__ hw1, const float* __restrict__ hb1,
                       const float* __restrict__ hw2, const float* __restrict__ hb2,
                       float* __restrict__ outp)
{
  __shared__ __align__(16) u16 sxh[LR * 64], sxl[LR * 64];     // residual hi/lo
  __shared__ __align__(16) u16 szh[LR * 128], szl[LR * 128];   // xc -> y hi/lo
  __shared__ __align__(16) u16 szb[LR * 128];                  // z (bf16 single)
  __shared__ __align__(16) float sproj[LR * 48];               // proj; later h1
  __shared__ float spart[4][LR][2];
  __shared__ float sbc[LR];

  const int tid = threadIdx.x;
  const int wv = tid >> 6, lane = tid & 63;
  const int col16 = lane & 15, g = lane >> 4;
  const int r0 = blockIdx.x * BR;

  // ---- Phase 0: x0 = feat @ Wf + bf (folded through NC). rows 0-31 nr, 32-63 r
  for (int idx = tid; idx < LR * 64; idx += 512) {
    int r = idx >> 6, c = idx & 63;
    const float* xr = xin + (size_t)(r0 + (r & 31)) * 16;
    float acc;
    if (r < 32) {
      acc = wsf[768 + c];
      #pragma unroll
      for (int i = 0; i < 12; ++i) acc = fmaf(xr[i], wsf[i * 64 + c], acc);
    } else {
      acc = wsf[1088 + c];
      #pragma unroll
      for (int i = 0; i < 4; ++i) acc = fmaf(xr[12 + i], wsf[832 + i * 64 + c], acc);
    }
    u16 h, lo; splitbf(acc, h, lo);
    int di = sxIdx(r, c); sxh[di] = h; sxl[di] = lo;
  }

  for (int l = 0; l < NLAY; ++l) {
    __syncthreads();
    // ---- Phase 1: xz = x @ ipwT (M=64,K=64,N=256), weight-stationary,
    //      serialized tiles. Wave owns n-tiles {2wv, 2wv+1}: wv<4 -> xc,
    //      wv>=4 -> z. 48 MFMA/wave, W-frags held across the 4 row tiles.
    {
      const u16* iph = wsu + U_IPH + l * 16384;
      const u16* ipl_ = wsu + U_IPL + l * 16384;
      const bool isZ = (wv >= 4);
      #pragma unroll 1
      for (int tt = 0; tt < 2; ++tt) {
        const int tile = 2 * wv + tt;          // 0..15
        const int n = tile * 16 + col16;
        // W frags for both k-halves, held across all 4 row-tiles
        bf8v Wh0 = *(const bf8v*)&iph[n * 64 + g * 8];
        bf8v Wl0 = *(const bf8v*)&ipl_[n * 64 + g * 8];
        bf8v Wh1 = *(const bf8v*)&iph[n * 64 + 32 + g * 8];
        bf8v Wl1 = *(const bf8v*)&ipl_[n * 64 + 32 + g * 8];
        float c3 = 0.f, cc = 0.f;
        int colx = (tile & 7) * 16 + col16;    // output col within its half
        if (!isZ) {
          c3 = cw[(size_t)l * 512 + colx * 4 + 3];
          cc = cbi[(size_t)l * 128 + colx];
        }
        #pragma unroll 1
        for (int rt = 0; rt < 4; ++rt) {
          const int rowA = rt * 16 + col16;
          bf8v Ah0 = *(const bf8v*)&sxh[rowA * 64 + (((g ^ rowA) & 7) << 3)];
          bf8v Al0 = *(const bf8v*)&sxl[rowA * 64 + (((g ^ rowA) & 7) << 3)];
          bf8v Ah1 = *(const bf8v*)&sxh[rowA * 64 + ((((4 + g) ^ rowA) & 7) << 3)];
          bf8v Al1 = *(const bf8v*)&sxl[rowA * 64 + ((((4 + g) ^ rowA) & 7) << 3)];
          f32x4 acc = {0, 0, 0, 0};
          acc = MFMA16(Ah0, Wh0, acc);
          acc = MFMA16(Al0, Wh0, acc);
          acc = MFMA16(Ah0, Wl0, acc);
          acc = MFMA16(Ah1, Wh1, acc);
          acc = MFMA16(Al1, Wh1, acc);
          acc = MFMA16(Ah1, Wl1, acc);
          #pragma unroll
          for (int j = 0; j < 4; ++j) {
            int row = rt * 16 + g * 4 + j;
            if (!isZ) {                        // xc: conv tap3 + silu -> hi/lo
              float v = siluf(fmaf(acc[j], c3, cc));
              u16 h, lo; splitbf(v, h, lo);
              int di = szIdx(row, colx);
              szh[di] = h; szl[di] = lo;
            } else {                           // z: silu -> single bf16
              szb[szIdx(row, colx)] = f2b(siluf(acc[j]));
            }
          }
        }
      }
    }
    __syncthreads();
    // ---- Phase 2: proj = xc @ xpwT (M=64,K=128,N=48). 12 tasks over 8 waves:
    //      wv<4: (rt=wv, nt=0,1); wv>=4: (rt=wv-4, nt=2).
    {
      const u16* xph = wsu + U_XPH + l * 6144;
      const u16* xpl = wsu + U_XPL + l * 6144;
      const int rt = wv & 3;
      const int rowA = rt * 16 + col16;
      const int ntasks = (wv < 4) ? 2 : 1;
      #pragma unroll 1
      for (int q = 0; q < ntasks; ++q) {
        const int nt = (wv < 4) ? q : 2;
        const int n2 = nt * 16 + col16;
        f32x4 C = {0, 0, 0, 0};
        #pragma unroll
        for (int ks = 0; ks < 4; ++ks) {
          int ch = ks * 4 + g;
          int ai = rowA * 128 + (((ch & 8) | ((ch ^ rowA) & 7)) << 3);
          bf8v Ah = *(const bf8v*)&szh[ai];
          bf8v Al = *(const bf8v*)&szl[ai];
          bf8v Wh = *(const bf8v*)&xph[n2 * 128 + ks * 32 + g * 8];
          bf8v Wl = *(const bf8v*)&xpl[n2 * 128 + ks * 32 + g * 8];
          C = MFMA16(Ah, Wh, C);
          C = MFMA16(Al, Wh, C);
          C = MFMA16(Ah, Wl, C);
        }
        #pragma unroll
        for (int j = 0; j < 4; ++j)
          sproj[(rt * 16 + g * 4 + j) * 48 + nt * 16 + col16] = C[j];
      }
    }
    __syncthreads();
    // ---- Phase 3: bc[r] = Bm . Cm  (scan collapses: h = dBx at L=1)
    {
      int r = tid >> 3, s = tid & 7;
      float v = sproj[r * 48 + 4 + s] * sproj[r * 48 + 20 + s]
              + sproj[r * 48 + 12 + s] * sproj[r * 48 + 28 + s];
      v += __shfl_xor(v, 1); v += __shfl_xor(v, 2); v += __shfl_xor(v, 4);
      if (s == 0) sbc[r] = v;
    }
    __syncthreads();
    // ---- Phase 4: dt = softplus(proj[:,:4]@dtw+dtb); y = xc*(dt*bc+ds)*z
    //      Wave w: rows rt=w&3, cols [(w>>2)*64, +64). All from LDS.
    {
      const int rt = wv & 3;
      const int ctb = (wv >> 2) * 4;
      #pragma unroll 1
      for (int t = 0; t < 4; ++t) {
        int col = (ctb + t) * 16 + col16;
        float w0 = dtw[(size_t)l * 512 + col];
        float w1 = dtw[(size_t)l * 512 + 128 + col];
        float w2 = dtw[(size_t)l * 512 + 256 + col];
        float w3 = dtw[(size_t)l * 512 + 384 + col];
        float bb = dtb[(size_t)l * 128 + col];
        float ds = dskip[(size_t)l * 128 + col];
        #pragma unroll
        for (int j = 0; j < 4; ++j) {
          int r = rt * 16 + g * 4 + j;
          float4 pj = *(const float4*)&sproj[r * 48];
          float dtv = softplusf(fmaf(pj.w, w3, fmaf(pj.z, w2, fmaf(pj.y, w1, fmaf(pj.x, w0, bb)))));
          int di = szIdx(r, col);
          float xc = b2f(szh[di]) + b2f(szl[di]);
          float zv = b2f(szb[di]);
          float y = xc * fmaf(dtv, sbc[r], ds) * zv;
          u16 h, lo; splitbf(y, h, lo);
          szh[di] = h; szl[di] = lo;
        }
      }
    }
    __syncthreads();
    // ---- Phase 5: o = y @ opwT (M=64,K=128,N=64). 16 tasks / 8 waves:
    //      wave w: nt = w&3, row-pair rtp = w>>2 -> rts {2rtp, 2rtp+1}.
    f32x4 O0 = {0,0,0,0}, O1 = {0,0,0,0};
    {
      const u16* oph = wsu + U_OPH + l * 8192;
      const u16* opl = wsu + U_OPL + l * 8192;
      const int nt = wv & 3, rtp = wv >> 2;
      const int n = nt * 16 + col16;
      #pragma unroll
      for (int ks = 0; ks < 4; ++ks) {
        bf8v Wh = *(const bf8v*)&oph[n * 128 + ks * 32 + g * 8];
        bf8v Wl = *(const bf8v*)&opl[n * 128 + ks * 32 + g * 8];
        int ch = ks * 4 + g;
        #pragma unroll
        for (int rr = 0; rr < 2; ++rr) {
          int rowA = (2 * rtp + rr) * 16 + col16;
          int ai = rowA * 128 + (((ch & 8) | ((ch ^ rowA) & 7)) << 3);
          bf8v Ah = *(const bf8v*)&szh[ai];
          bf8v Al = *(const bf8v*)&szl[ai];
          if (rr == 0) {
            O0 = MFMA16(Ah, Wh, O0); O0 = MFMA16(Al, Wh, O0); O0 = MFMA16(Ah, Wl, O0);
          } else {
            O1 = MFMA16(Ah, Wh, O1); O1 = MFMA16(Al, Wh, O1); O1 = MFMA16(Ah, Wl, O1);
          }
        }
      }
      #pragma unroll
      for (int rr = 0; rr < 2; ++rr) {
        #pragma unroll
        for (int j = 0; j < 4; ++j) {
          float o = (rr == 0) ? O0[j] : O1[j];
          float s1 = o, s2 = o * o;
          s1 += __shfl_xor(s1, 1); s2 += __shfl_xor(s2, 1);
          s1 += __shfl_xor(s1, 2); s2 += __shfl_xor(s2, 2);
          s1 += __shfl_xor(s1, 4); s2 += __shfl_xor(s2, 4);
          s1 += __shfl_xor(s1, 8); s2 += __shfl_xor(s2, 8);
          if (col16 == 0) {
            int row = (2 * rtp + rr) * 16 + g * 4 + j;
            spart[nt][row][0] = s1; spart[nt][row][1] = s2;
          }
        }
      }
    }
    __syncthreads();
    // ---- Phase 6: LN stats per lane + x += LN(o)*g + b (O0/O1 still live)
    {
      const int nt = wv & 3, rtp = wv >> 2;
      int col = nt * 16 + col16;
      float gv = lng[(size_t)l * 64 + col], bv = lnb[(size_t)l * 64 + col];
      #pragma unroll
      for (int rr = 0; rr < 2; ++rr) {
        #pragma unroll
        for (int j = 0; j < 4; ++j) {
          int row = (2 * rtp + rr) * 16 + g * 4 + j;
          float s1 = spart[0][row][0] + spart[1][row][0] + spart[2][row][0] + spart[3][row][0];
          float s2 = spart[0][row][1] + spart[1][row][1] + spart[2][row][1] + spart[3][row][1];
          float m = s1 * (1.f / 64);
          float var = s2 * (1.f / 64) - m * m;
          float rstd = rsqrtf(var + 1e-5f);
          float o = (rr == 0) ? O0[j] : O1[j];
          float v = fmaf((o - m) * rstd, gv, bv);
          int di = sxIdx(row, col);
          float nv = b2f(sxh[di]) + b2f(sxl[di]) + v;
          u16 h, lo; splitbf(nv, h, lo);
          sxh[di] = h; sxl[di] = lo;
        }
      }
    }
  }
  __syncthreads();
  // ---- Head stage A: transpose hw1 [128][32] -> szh/szl rows 0-31 (swizzled)
  {
    int k = tid >> 2, n0 = (tid & 3) * 8;
    const float* src = hw1 + (size_t)k * 32 + n0;
    #pragma unroll
    for (int i = 0; i < 8; ++i) {
      u16 h, lo; splitbf(src[i], h, lo);
      int di = szIdx(n0 + i, k);
      szh[di] = h; szl[di] = lo;
    }
  }
  __syncthreads();
  // ---- Head stage B: h1 = relu([x_nr|x_r] @ hw1 + hb1), waves 0-3:
  //      (mt = w&1, nt = w>>1). A rows: logical row = m + (k>=64 ? 32 : 0).
  if (wv < 4) {
    const int mt = wv & 1, nt = wv >> 1;
    const int m16 = mt * 16 + col16;
    const int nB = nt * 16 + col16;
    f32x4 H = {0, 0, 0, 0};
    #pragma unroll
    for (int ks = 0; ks < 4; ++ks) {
      int kg = ks * 32 + g * 8;
      int arow = m16 + ((kg >> 6) << 5);     // +32 for rain half
      int ai = sxIdx(arow, kg & 63);
      bf8v Ah = *(const bf8v*)&sxh[ai];
      bf8v Al = *(const bf8v*)&sxl[ai];
      int bi = szIdx(nB, kg);
      bf8v Bh = *(const bf8v*)&szh[bi];
      bf8v Bl = *(const bf8v*)&szl[bi];
      H = MFMA16(Ah, Bh, H);
      H = MFMA16(Al, Bh, H);
      H = MFMA16(Ah, Bl, H);
    }
    float bias = hb1[nB];
    #pragma unroll
    for (int j = 0; j < 4; ++j) {
      int m = mt * 16 + g * 4 + j;
      sproj[m * 48 + nB] = fmaxf(H[j] + bias, 0.f);
    }
  }
  __syncthreads();
  // ---- Head stage C: out = h1 @ hw2 + hb2
  if (tid < 256) {
    int m = tid >> 3, s = tid & 7;
    float acc = sproj[m * 48 + s] * hw2[s]
              + sproj[m * 48 + 8 + s] * hw2[8 + s]
              + sproj[m * 48 + 16 + s] * hw2[16 + s]
              + sproj[m * 48 + 24 + s] * hw2[24 + s];
    acc += __shfl_xor(acc, 1); acc += __shfl_xor(acc, 2); acc += __shfl_xor(acc, 4);
    if (s == 0) outp[r0 + m] = acc + hb2[0];
  }
}

extern "C" void kernel_launch(void* const* d_in, const int* in_sizes, int n_in,
                              void* d_out, int out_size, void* d_ws, size_t ws_size,
                              hipStream_t stream) {
  const float* x      = (const float*)d_in[0];
  const float* w_nr   = (const float*)d_in[1];
  const float* b_nr   = (const float*)d_in[2];
  const float* w_r    = (const float*)d_in[3];
  const float* b_r    = (const float*)d_in[4];
  const float* win_nr = (const float*)d_in[5];
  const float* bin_nr = (const float*)d_in[6];
  const float* win_r  = (const float*)d_in[7];
  const float* bin_r  = (const float*)d_in[8];
  const float* ipw    = (const float*)d_in[9];
  const float* cw     = (const float*)d_in[10];
  const float* cb     = (const float*)d_in[11];
  const float* xpw    = (const float*)d_in[12];
  const float* dtw    = (const float*)d_in[13];
  const float* dtb    = (const float*)d_in[14];
  // d_in[15] = alog: dead at L=1 (scan from h=0 uses only dBx)
  const float* dskip  = (const float*)d_in[16];
  const float* opw    = (const float*)d_in[17];
  const float* lng    = (const float*)d_in[18];
  const float* lnb    = (const float*)d_in[19];
  const float* hw1    = (const float*)d_in[20];
  const float* hb1    = (const float*)d_in[21];
  const float* hw2    = (const float*)d_in[22];
  const float* hb2    = (const float*)d_in[23];
  float* wsf = (float*)d_ws;
  u16*   wsu = (u16*)d_ws;
  float* out = (float*)d_out;

  prep_all_kernel<<<42, 256, 0, stream>>>(w_nr, b_nr, w_r, b_r,
                                          win_nr, bin_nr, win_r, bin_r,
                                          ipw, xpw, opw, wsf, wsu);
  mamba_main_kernel<<<16384 / BR, 512, 0, stream>>>(x, wsf, wsu, cw, cb,
                                                    dtw, dtb, dskip, lng, lnb,
                                                    hw1, hb1, hw2, hb2, out);
}